// Round 3
// baseline (233.943 us; speedup 1.0000x reference)
//
#include <hip/hip_runtime.h>
#include <hip/hip_bf16.h>

// Problem constants
constexpr int BATCH = 4096;
constexpr int IN    = 512;
constexpr int OUT   = 512;
constexpr int ORD   = 8;
constexpr int NK    = ORD + 1;        // 9
constexpr float FA  = 1.0f, FB = 1.0f;

// GEMM inner dim EXCLUDES k=0 (J0 == 1 -> constant bias term handled separately)
constexpr int KP     = IN * ORD;               // 4096
constexpr int SPLITK = 4;                      // 512 blocks -> 2 blocks/CU
constexpr int KT     = KP / (32 * SPLITK);     // 32 K-tile iters per block

typedef __attribute__((ext_vector_type(8))) short short8;   // 8 bf16 = 4 VGPRs
typedef __attribute__((ext_vector_type(4))) float floatx4;  // MFMA C/D

#define AS1 __attribute__((address_space(1)))
#define AS3 __attribute__((address_space(3)))

__device__ __forceinline__ void gload_lds16(const void* g, void* l) {
    // async global->LDS, 16B/lane; LDS dest = wave-uniform base + lane*16
    __builtin_amdgcn_global_load_lds((const AS1 unsigned int*)g,
                                     (AS3 unsigned int*)l, 16, 0, 0);
}

__device__ __forceinline__ float bf16bits_to_f32(short s) {
    union { unsigned int u; float f; } cv;
    cv.u = ((unsigned int)(unsigned short)s) << 16;
    return cv.f;
}

// ---------------------------------------------------------------------------
// Kernel 1 (fused prep):
//   blocks [0, 8192):      J[b, (k-1)*512 + i] = bf16( J_k(tanh(x[b,i])) ), k=1..8
//   blocks [8192, 9216):   Cb[o, (k-1)*512 + i] = bf16( coeff[o,i,k] * w[o,i] )
//   blocks [9216, 9218):   bias[o] = sum_i coeff[o,i,0] * w[o,i]   (J0 == 1)
// ---------------------------------------------------------------------------
__global__ __launch_bounds__(256) void prep(const float* __restrict__ x,
                                            const float* __restrict__ w,
                                            const float* __restrict__ coeff,
                                            __hip_bfloat16* __restrict__ J,
                                            __hip_bfloat16* __restrict__ Cb,
                                            float* __restrict__ bias) {
    const int bid = blockIdx.x;
    if (bid < BATCH * IN / 256) {
        // ---- Jacobi branch ----
        int idx = bid * 256 + threadIdx.x;          // [0, 4096*512)
        float xv = x[idx];
        float xc = fminf(fmaxf(xv, -9.0f), 9.0f);   // exact to bf16 beyond |x|=9
        float e  = __expf(2.0f * xc);
        float t  = (e - 1.0f) / (e + 1.0f);
        int b = idx >> 9, i = idx & 511;
        __hip_bfloat16* row = J + (size_t)b * KP + i;   // stride 512 per order
        float p0 = 1.0f;
        float p1 = 0.5f * (FA + FB + 2.0f) * t - 0.5f * (FA - FB);
        row[0] = __float2bfloat16(p1);                  // order 1 at plane 0
#pragma unroll
        for (int n = 2; n <= ORD; ++n) {
            float fn = (float)n;
            float k1 = (2.f*fn+FA+FB)*(2.f*fn+FA+FB-1.f) / (2.f*fn*(fn+FA+FB));
            float k2 = (2.f*fn+FA+FB-1.f)*(FA*FA-FB*FB) /
                       (2.f*fn*(fn+FA+FB)*(2.f*fn+FA+FB-2.f));
            float k3 = (fn+FA-1.f)*(fn+FB-1.f)*(2.f*fn+FA+FB) /
                       (fn*(fn+FA+FB)*(2.f*fn+FA+FB-2.f));
            float p2 = (k1*t + k2)*p1 - k3*p0;
            row[(n - 1) * 512] = __float2bfloat16(p2);
            p0 = p1; p1 = p2;
        }
    } else if (bid < BATCH * IN / 256 + OUT * IN / 256) {
        // ---- coeff*w branch (orders 1..8) ----
        int idx = (bid - BATCH * IN / 256) * 256 + threadIdx.x;  // [0, 512*512)
        float wv = w[idx];
        const float* cf = coeff + (size_t)idx * NK;
        int o = idx >> 9, i = idx & 511;
        __hip_bfloat16* row = Cb + (size_t)o * KP + i;
#pragma unroll
        for (int k = 1; k <= ORD; ++k)
            row[(k - 1) * 512] = __float2bfloat16(cf[k] * wv);
    } else {
        // ---- bias branch: 2 blocks, thread = output o ----
        int o = (bid - (BATCH * IN / 256 + OUT * IN / 256)) * 256 + threadIdx.x;
        float acc = 0.0f;
        const float* cf = coeff + (size_t)o * IN * NK;   // [i][k], k fastest
        const float* wr = w + (size_t)o * IN;
        for (int i = 0; i < IN; ++i)
            acc = fmaf(cf[(size_t)i * NK], wr[i], acc);
        bias[o] = acc;
    }
}

// ---------------------------------------------------------------------------
// Kernel 2: split-K GEMM  P[z][m][n] = bf16( sum_{k in chunk z} A[m,k]*B[n,k] )
// 128x128x32 tile, 256 threads (2x2 waves, 64x64/wave, 4x4 MFMA frags)
// ---------------------------------------------------------------------------
__global__ __launch_bounds__(256, 2) void gemm_splitk(
        const __hip_bfloat16* __restrict__ A,   // [4096][4096]
        const __hip_bfloat16* __restrict__ B,   // [512][4096]
        __hip_bfloat16* __restrict__ P)         // [SPLITK][4096][512] bf16
{
    __shared__ __hip_bfloat16 sA[128 * 32];
    __shared__ __hip_bfloat16 sB[128 * 32];

    const int tid = threadIdx.x;
    const int m0 = blockIdx.x * 128;
    const int n0 = blockIdx.y * 128;
    const int z  = blockIdx.z;

    // staging: thread t loads 16B at (row = t/4, col8 = t&3)
    const int lrow = tid >> 2;
    const int lcol = (tid & 3) * 8;
    const __hip_bfloat16* ga = A + (size_t)(m0 + lrow) * KP + z * (KT * 32) + lcol;
    const __hip_bfloat16* gb = B + (size_t)(n0 + lrow) * KP + z * (KT * 32) + lcol;
    __hip_bfloat16* la = sA + tid * 8;
    __hip_bfloat16* lb = sB + tid * 8;

    // fragment addressing: A[m=lane&15][k=quad*8+j]
    const int lane = tid & 63;
    const int quad = lane >> 4;
    const int l15  = lane & 15;
    const int mw   = (tid >> 6) & 1;
    const int nw   = tid >> 7;
    const int aBase = (mw * 64 + l15) * 32 + quad * 8;
    const int bBase = (nw * 64 + l15) * 32 + quad * 8;

    floatx4 acc[4][4];
#pragma unroll
    for (int i = 0; i < 4; ++i)
#pragma unroll
        for (int j = 0; j < 4; ++j) acc[i][j] = (floatx4)0.0f;

    for (int kt = 0; kt < KT; ++kt) {
        gload_lds16(ga,                   la);
        gload_lds16(ga + (size_t)64 * KP, la + 2048);
        gload_lds16(gb,                   lb);
        gload_lds16(gb + (size_t)64 * KP, lb + 2048);
        ga += 32; gb += 32;
        __syncthreads();   // drains vmcnt (global_load_lds) + barrier

        short8 af[4], bfr[4];
#pragma unroll
        for (int i = 0; i < 4; ++i)
            af[i] = *(const short8*)(sA + aBase + i * 16 * 32);
#pragma unroll
        for (int j = 0; j < 4; ++j)
            bfr[j] = *(const short8*)(sB + bBase + j * 16 * 32);
#pragma unroll
        for (int i = 0; i < 4; ++i)
#pragma unroll
            for (int j = 0; j < 4; ++j)
                acc[i][j] = __builtin_amdgcn_mfma_f32_16x16x32_bf16(
                                af[i], bfr[j], acc[i][j], 0, 0, 0);
        __syncthreads();   // protect LDS before next stage
    }

    // epilogue: C/D layout col = lane&15, row = quad*4 + reg; store bf16 partials
    __hip_bfloat16* Pz = P + (size_t)z * BATCH * OUT;
#pragma unroll
    for (int i = 0; i < 4; ++i) {
        const int r0 = m0 + mw * 64 + i * 16 + quad * 4;
#pragma unroll
        for (int j = 0; j < 4; ++j) {
            const int c = n0 + nw * 64 + j * 16 + l15;
#pragma unroll
            for (int r = 0; r < 4; ++r)
                Pz[(size_t)(r0 + r) * OUT + c] = __float2bfloat16(acc[i][j][r]);
        }
    }
}

// ---------------------------------------------------------------------------
// Kernel 3: out[b,o] = sum_z P[z][b,o] + bias[o]   (8 outputs per thread)
// ---------------------------------------------------------------------------
__global__ __launch_bounds__(256) void reducek(const short* __restrict__ P,
                                               const float* __restrict__ bias,
                                               float* __restrict__ out) {
    const int j = blockIdx.x * 256 + threadIdx.x;   // [0, 2M/8)
    const size_t base = (size_t)j * 8;
    constexpr size_t PLANE = (size_t)BATCH * OUT;   // 2M elements

    float s[8];
    {
        short8 v = *(const short8*)(P + base);
#pragma unroll
        for (int e = 0; e < 8; ++e) s[e] = bf16bits_to_f32(v[e]);
    }
#pragma unroll
    for (int z = 1; z < SPLITK; ++z) {
        short8 v = *(const short8*)(P + z * PLANE + base);
#pragma unroll
        for (int e = 0; e < 8; ++e) s[e] += bf16bits_to_f32(v[e]);
    }
    const int o0 = (int)(base & (OUT - 1));
    const floatx4 b0 = *(const floatx4*)(bias + o0);
    const floatx4 b1 = *(const floatx4*)(bias + o0 + 4);
    floatx4 r0 = {s[0] + b0[0], s[1] + b0[1], s[2] + b0[2], s[3] + b0[3]};
    floatx4 r1 = {s[4] + b1[0], s[5] + b1[1], s[6] + b1[2], s[7] + b1[3]};
    *(floatx4*)(out + base)     = r0;
    *(floatx4*)(out + base + 4) = r1;
}

// ---------------------------------------------------------------------------
extern "C" void kernel_launch(void* const* d_in, const int* in_sizes, int n_in,
                              void* d_out, int out_size, void* d_ws, size_t ws_size,
                              hipStream_t stream) {
    const float* x     = (const float*)d_in[0];   // [4096,512]
    const float* w     = (const float*)d_in[1];   // [512,512]
    const float* coeff = (const float*)d_in[2];   // [512,512,9]
    float* out = (float*)d_out;                   // [4096,512]

    // workspace layout (bytes)
    char* ws = (char*)d_ws;
    __hip_bfloat16* J  = (__hip_bfloat16*)ws;                          // 33,554,432 B
    char* p1c = ws + (size_t)BATCH * KP * 2;
    __hip_bfloat16* Cb = (__hip_bfloat16*)p1c;                         //  4,194,304 B
    char* p2c = p1c + (size_t)OUT * KP * 2;
    __hip_bfloat16* P  = (__hip_bfloat16*)p2c;                         // 16,777,216 B
    float* bias = (float*)(p2c + (size_t)SPLITK * BATCH * OUT * 2);    //      2,048 B

    const int prep_blocks = BATCH * IN / 256 + OUT * IN / 256 + OUT / 256;
    prep<<<prep_blocks, 256, 0, stream>>>(x, w, coeff, J, Cb, bias);
    gemm_splitk<<<dim3(BATCH / 128, OUT / 128, SPLITK), 256, 0, stream>>>(J, Cb, P);
    reducek<<<BATCH * OUT / 8 / 256, 256, 0, stream>>>((const short*)P, bias, out);
}

// Round 5
// 108.399 us; speedup vs baseline: 2.1582x; 2.1582x over previous
//
#include <hip/hip_runtime.h>
#include <hip/hip_bf16.h>

// Problem constants
constexpr int BATCH = 4096;
constexpr int IN    = 512;
constexpr int OUT   = 512;
constexpr int ORD   = 8;
constexpr int NK    = ORD + 1;        // 9
constexpr float FA  = 1.0f, FB = 1.0f;

// GEMM inner dim EXCLUDES k=0 (J0 == 1 -> constant bias term handled separately)
constexpr int KP     = IN * ORD;               // 4096
constexpr int SPLITK = 4;                      // 512 blocks -> 2 blocks/CU
constexpr int KT     = KP / (32 * SPLITK);     // 32 K-tile iters per block

typedef __attribute__((ext_vector_type(8))) short short8;   // 8 bf16 = 4 VGPRs
typedef __attribute__((ext_vector_type(4))) float floatx4;  // MFMA C/D

#define AS1 __attribute__((address_space(1)))
#define AS3 __attribute__((address_space(3)))

__device__ __forceinline__ void gload_lds16(const void* g, void* l) {
    // async global->LDS, 16B/lane; LDS dest = wave-uniform base + lane*16
    __builtin_amdgcn_global_load_lds((const AS1 unsigned int*)g,
                                     (AS3 unsigned int*)l, 16, 0, 0);
}

__device__ __forceinline__ float bf16bits_to_f32(short s) {
    union { unsigned int u; float f; } cv;
    cv.u = ((unsigned int)(unsigned short)s) << 16;
    return cv.f;
}

// ---------------------------------------------------------------------------
// Kernel 1 (fused prep):
//   blocks [0, 8192):        J[b, (k-1)*512 + i] = bf16( J_k(tanh(x[b,i])) )
//   blocks [8192, 9216):     Cb[o, (k-1)*512 + i] = bf16( coeff[o,i,k] * w[o,i] )
//   blocks [9216, 9216+128): bias[o] = sum_i coeff[o,i,0]*w[o,i]  (1 wave per o)
// ---------------------------------------------------------------------------
__global__ __launch_bounds__(256) void prep(const float* __restrict__ x,
                                            const float* __restrict__ w,
                                            const float* __restrict__ coeff,
                                            __hip_bfloat16* __restrict__ J,
                                            __hip_bfloat16* __restrict__ Cb,
                                            float* __restrict__ bias) {
    const int bid = blockIdx.x;
    if (bid < BATCH * IN / 256) {
        // ---- Jacobi branch ----
        int idx = bid * 256 + threadIdx.x;          // [0, 4096*512)
        float xv = x[idx];
        float xc = fminf(fmaxf(xv, -9.0f), 9.0f);   // exact to bf16 beyond |x|=9
        float e  = __expf(2.0f * xc);
        float t  = (e - 1.0f) / (e + 1.0f);
        int b = idx >> 9, i = idx & 511;
        __hip_bfloat16* row = J + (size_t)b * KP + i;   // stride 512 per order
        float p0 = 1.0f;
        float p1 = 0.5f * (FA + FB + 2.0f) * t - 0.5f * (FA - FB);
        row[0] = __float2bfloat16(p1);                  // order 1 at plane 0
#pragma unroll
        for (int n = 2; n <= ORD; ++n) {
            float fn = (float)n;
            float k1 = (2.f*fn+FA+FB)*(2.f*fn+FA+FB-1.f) / (2.f*fn*(fn+FA+FB));
            float k2 = (2.f*fn+FA+FB-1.f)*(FA*FA-FB*FB) /
                       (2.f*fn*(fn+FA+FB)*(2.f*fn+FA+FB-2.f));
            float k3 = (fn+FA-1.f)*(fn+FB-1.f)*(2.f*fn+FA+FB) /
                       (fn*(fn+FA+FB)*(2.f*fn+FA+FB-2.f));
            float p2 = (k1*t + k2)*p1 - k3*p0;
            row[(n - 1) * 512] = __float2bfloat16(p2);
            p0 = p1; p1 = p2;
        }
    } else if (bid < BATCH * IN / 256 + OUT * IN / 256) {
        // ---- coeff*w branch (orders 1..8) ----
        int idx = (bid - BATCH * IN / 256) * 256 + threadIdx.x;  // [0, 512*512)
        float wv = w[idx];
        const float* cf = coeff + (size_t)idx * NK;
        int o = idx >> 9, i = idx & 511;
        __hip_bfloat16* row = Cb + (size_t)o * KP + i;
#pragma unroll
        for (int k = 1; k <= ORD; ++k)
            row[(k - 1) * 512] = __float2bfloat16(cf[k] * wv);
    } else {
        // ---- bias branch: 128 blocks, one wave per output o ----
        const int bb   = bid - (BATCH * IN / 256 + OUT * IN / 256);  // 0..127
        const int lane = threadIdx.x & 63;
        const int o    = bb * 4 + (threadIdx.x >> 6);                // wave id -> o
        const float* cf = coeff + (size_t)o * IN * NK;               // [i][k]
        const float* wr = w + (size_t)o * IN;
        float acc = 0.0f;
#pragma unroll
        for (int r = 0; r < IN / 64; ++r) {
            int i = r * 64 + lane;
            acc = fmaf(cf[(size_t)i * NK], wr[i], acc);
        }
#pragma unroll
        for (int off = 32; off >= 1; off >>= 1)
            acc += __shfl_xor(acc, off, 64);
        if (lane == 0) bias[o] = acc;
    }
}

// ---------------------------------------------------------------------------
// Kernel 2: split-K GEMM  P[z][m][n] = bf16( sum_{k in chunk z} A[m,k]*B[n,k] )
// 128x128x32 tile, 256 threads (2x2 waves, 64x64/wave, 4x4 MFMA frags)
// ---------------------------------------------------------------------------
__global__ __launch_bounds__(256, 2) void gemm_splitk(
        const __hip_bfloat16* __restrict__ A,   // [4096][4096]
        const __hip_bfloat16* __restrict__ B,   // [512][4096]
        __hip_bfloat16* __restrict__ P)         // [SPLITK][4096][512] bf16
{
    __shared__ __hip_bfloat16 sA[128 * 32];
    __shared__ __hip_bfloat16 sB[128 * 32];

    const int tid = threadIdx.x;
    const int m0 = blockIdx.x * 128;
    const int n0 = blockIdx.y * 128;
    const int z  = blockIdx.z;

    // staging: thread t loads 16B at (row = t/4, col8 = t&3)
    const int lrow = tid >> 2;
    const int lcol = (tid & 3) * 8;
    const __hip_bfloat16* ga = A + (size_t)(m0 + lrow) * KP + z * (KT * 32) + lcol;
    const __hip_bfloat16* gb = B + (size_t)(n0 + lrow) * KP + z * (KT * 32) + lcol;
    __hip_bfloat16* la = sA + tid * 8;
    __hip_bfloat16* lb = sB + tid * 8;

    // fragment addressing: A[m=lane&15][k=quad*8+j]
    const int lane = tid & 63;
    const int quad = lane >> 4;
    const int l15  = lane & 15;
    const int mw   = (tid >> 6) & 1;
    const int nw   = tid >> 7;
    const int aBase = (mw * 64 + l15) * 32 + quad * 8;
    const int bBase = (nw * 64 + l15) * 32 + quad * 8;

    floatx4 acc[4][4];
#pragma unroll
    for (int i = 0; i < 4; ++i)
#pragma unroll
        for (int j = 0; j < 4; ++j) acc[i][j] = (floatx4)0.0f;

    for (int kt = 0; kt < KT; ++kt) {
        gload_lds16(ga,                   la);
        gload_lds16(ga + (size_t)64 * KP, la + 2048);
        gload_lds16(gb,                   lb);
        gload_lds16(gb + (size_t)64 * KP, lb + 2048);
        ga += 32; gb += 32;
        __syncthreads();   // drains vmcnt (global_load_lds) + barrier

        short8 af[4], bfr[4];
#pragma unroll
        for (int i = 0; i < 4; ++i)
            af[i] = *(const short8*)(sA + aBase + i * 16 * 32);
#pragma unroll
        for (int j = 0; j < 4; ++j)
            bfr[j] = *(const short8*)(sB + bBase + j * 16 * 32);
#pragma unroll
        for (int i = 0; i < 4; ++i)
#pragma unroll
            for (int j = 0; j < 4; ++j)
                acc[i][j] = __builtin_amdgcn_mfma_f32_16x16x32_bf16(
                                af[i], bfr[j], acc[i][j], 0, 0, 0);
        __syncthreads();   // protect LDS before next stage
    }

    // epilogue: C/D layout col = lane&15, row = quad*4 + reg; store bf16 partials
    __hip_bfloat16* Pz = P + (size_t)z * BATCH * OUT;
#pragma unroll
    for (int i = 0; i < 4; ++i) {
        const int r0 = m0 + mw * 64 + i * 16 + quad * 4;
#pragma unroll
        for (int j = 0; j < 4; ++j) {
            const int c = n0 + nw * 64 + j * 16 + l15;
#pragma unroll
            for (int r = 0; r < 4; ++r)
                Pz[(size_t)(r0 + r) * OUT + c] = __float2bfloat16(acc[i][j][r]);
        }
    }
}

// ---------------------------------------------------------------------------
// Kernel 3: out[b,o] = sum_z P[z][b,o] + bias[o]   (8 outputs per thread)
// ---------------------------------------------------------------------------
__global__ __launch_bounds__(256) void reducek(const short* __restrict__ P,
                                               const float* __restrict__ bias,
                                               float* __restrict__ out) {
    const int j = blockIdx.x * 256 + threadIdx.x;   // [0, 2M/8)
    const size_t base = (size_t)j * 8;
    constexpr size_t PLANE = (size_t)BATCH * OUT;   // 2M elements

    float s[8];
    {
        short8 v = *(const short8*)(P + base);
#pragma unroll
        for (int e = 0; e < 8; ++e) s[e] = bf16bits_to_f32(v[e]);
    }
#pragma unroll
    for (int z = 1; z < SPLITK; ++z) {
        short8 v = *(const short8*)(P + z * PLANE + base);
#pragma unroll
        for (int e = 0; e < 8; ++e) s[e] += bf16bits_to_f32(v[e]);
    }
    const int o0 = (int)(base & (OUT - 1));
    const floatx4 b0 = *(const floatx4*)(bias + o0);
    const floatx4 b1 = *(const floatx4*)(bias + o0 + 4);
    floatx4 r0 = {s[0] + b0[0], s[1] + b0[1], s[2] + b0[2], s[3] + b0[3]};
    floatx4 r1 = {s[4] + b1[0], s[5] + b1[1], s[6] + b1[2], s[7] + b1[3]};
    *(floatx4*)(out + base)     = r0;
    *(floatx4*)(out + base + 4) = r1;
}

// ---------------------------------------------------------------------------
extern "C" void kernel_launch(void* const* d_in, const int* in_sizes, int n_in,
                              void* d_out, int out_size, void* d_ws, size_t ws_size,
                              hipStream_t stream) {
    const float* x     = (const float*)d_in[0];   // [4096,512]
    const float* w     = (const float*)d_in[1];   // [512,512]
    const float* coeff = (const float*)d_in[2];   // [512,512,9]
    float* out = (float*)d_out;                   // [4096,512]

    // workspace layout (bytes)
    char* ws = (char*)d_ws;
    __hip_bfloat16* J  = (__hip_bfloat16*)ws;                          // 33,554,432 B
    char* p1c = ws + (size_t)BATCH * KP * 2;
    __hip_bfloat16* Cb = (__hip_bfloat16*)p1c;                         //  4,194,304 B
    char* p2c = p1c + (size_t)OUT * KP * 2;
    __hip_bfloat16* P  = (__hip_bfloat16*)p2c;                         // 16,777,216 B
    float* bias = (float*)(p2c + (size_t)SPLITK * BATCH * OUT * 2);    //      2,048 B

    // bias branch: OUT/4 = 128 blocks (4 waves/block, one wave per output o).
    // (Round-4 bug: OUT/4/64 launched only 2 bias blocks -> 504 outputs unbiased.)
    const int prep_blocks = BATCH * IN / 256 + OUT * IN / 256 + OUT / 4;
    prep<<<prep_blocks, 256, 0, stream>>>(x, w, coeff, J, Cb, bias);
    gemm_splitk<<<dim3(BATCH / 128, OUT / 128, SPLITK), 256, 0, stream>>>(J, Cb, P);
    reducek<<<BATCH * OUT / 8 / 256, 256, 0, stream>>>((const short*)P, bias, out);
}

// Round 6
// 107.834 us; speedup vs baseline: 2.1695x; 1.0052x over previous
//
#include <hip/hip_runtime.h>
#include <hip/hip_bf16.h>

// Problem constants
constexpr int BATCH = 4096;
constexpr int IN    = 512;
constexpr int OUT   = 512;
constexpr int ORD   = 8;
constexpr int NK    = ORD + 1;        // 9
constexpr float FA  = 1.0f, FB = 1.0f;

// GEMM inner dim EXCLUDES k=0 (J0 == 1 -> constant bias handled separately)
constexpr int KP     = IN * ORD;               // 4096
constexpr int SPLITK = 4;                      // 512 blocks -> 2 blocks/CU
constexpr int KT     = KP / (32 * SPLITK);     // 32 K-tile iters per block

typedef __attribute__((ext_vector_type(8))) short short8;   // 8 bf16 = 4 VGPRs
typedef __attribute__((ext_vector_type(4))) float floatx4;  // MFMA C/D

#define AS1 __attribute__((address_space(1)))
#define AS3 __attribute__((address_space(3)))

__device__ __forceinline__ void gload_lds16(const void* g, void* l) {
    // async global->LDS, 16B/lane; LDS dest = wave-uniform base + lane*16
    __builtin_amdgcn_global_load_lds((const AS1 unsigned int*)g,
                                     (AS3 unsigned int*)l, 16, 0, 0);
}

__device__ __forceinline__ float bf16bits_to_f32(short s) {
    union { unsigned int u; float f; } cv;
    cv.u = ((unsigned int)(unsigned short)s) << 16;
    return cv.f;
}

// ---------------------------------------------------------------------------
// Kernel 1 (fused prep), 2 elements per thread for vectorized stores:
//   blocks [0, 4096):        J[b, (k-1)*512 + i] = bf16( J_k(tanh(x[b,i])) )
//   blocks [4096, 4608):     Cb[o, (k-1)*512 + i] = bf16( coeff[o,i,k]*w[o,i] )
//   blocks [4608, 4736):     bias[o] = sum_i coeff[o,i,0]*w[o,i] (1 wave per o)
// ---------------------------------------------------------------------------
__global__ __launch_bounds__(256) void prep(const float* __restrict__ x,
                                            const float* __restrict__ w,
                                            const float* __restrict__ coeff,
                                            __hip_bfloat16* __restrict__ J,
                                            __hip_bfloat16* __restrict__ Cb,
                                            float* __restrict__ bias) {
    const int bid = blockIdx.x;
    if (bid < BATCH * IN / 512) {
        // ---- Jacobi branch: one thread handles i, i+1 ----
        int p = bid * 256 + threadIdx.x;            // pair index [0, 1M)
        float2 xv = *(const float2*)(x + (size_t)p * 2);
        float t0, t1;
        {
            float xc = fminf(fmaxf(xv.x, -9.0f), 9.0f);
            float e  = __expf(2.0f * xc);
            t0 = (e - 1.0f) / (e + 1.0f);
            xc = fminf(fmaxf(xv.y, -9.0f), 9.0f);
            e  = __expf(2.0f * xc);
            t1 = (e - 1.0f) / (e + 1.0f);
        }
        int b = p >> 8, i = (p * 2) & 511;
        __hip_bfloat16* row = J + (size_t)b * KP + i;   // stride 512 per order
        float a0 = 1.0f, a1 = 1.0f;
        float b0 = 0.5f * (FA + FB + 2.0f) * t0 - 0.5f * (FA - FB);
        float b1 = 0.5f * (FA + FB + 2.0f) * t1 - 0.5f * (FA - FB);
        *(__hip_bfloat162*)row = __hip_bfloat162{__float2bfloat16(b0),
                                                 __float2bfloat16(b1)};
#pragma unroll
        for (int n = 2; n <= ORD; ++n) {
            float fn = (float)n;
            float k1 = (2.f*fn+FA+FB)*(2.f*fn+FA+FB-1.f) / (2.f*fn*(fn+FA+FB));
            float k2 = (2.f*fn+FA+FB-1.f)*(FA*FA-FB*FB) /
                       (2.f*fn*(fn+FA+FB)*(2.f*fn+FA+FB-2.f));
            float k3 = (fn+FA-1.f)*(fn+FB-1.f)*(2.f*fn+FA+FB) /
                       (fn*(fn+FA+FB)*(2.f*fn+FA+FB-2.f));
            float c0 = (k1*t0 + k2)*b0 - k3*a0;
            float c1 = (k1*t1 + k2)*b1 - k3*a1;
            *(__hip_bfloat162*)(row + (n - 1) * 512) =
                __hip_bfloat162{__float2bfloat16(c0), __float2bfloat16(c1)};
            a0 = b0; b0 = c0; a1 = b1; b1 = c1;
        }
    } else if (bid < BATCH * IN / 512 + OUT * IN / 512) {
        // ---- coeff*w branch: one thread handles i, i+1 ----
        int p = (bid - BATCH * IN / 512) * 256 + threadIdx.x;  // [0, 131072)
        float2 wv = *(const float2*)(w + (size_t)p * 2);
        const float* cf0 = coeff + (size_t)p * 2 * NK;
        const float* cf1 = cf0 + NK;
        int o = p >> 8, i = (p * 2) & 511;
        __hip_bfloat16* row = Cb + (size_t)o * KP + i;
#pragma unroll
        for (int k = 1; k <= ORD; ++k)
            *(__hip_bfloat162*)(row + (k - 1) * 512) =
                __hip_bfloat162{__float2bfloat16(cf0[k] * wv.x),
                                __float2bfloat16(cf1[k] * wv.y)};
    } else {
        // ---- bias branch: 128 blocks, one wave per output o ----
        const int bb   = bid - (BATCH * IN / 512 + OUT * IN / 512);  // 0..127
        const int lane = threadIdx.x & 63;
        const int o    = bb * 4 + (threadIdx.x >> 6);                // wave -> o
        const float* cf = coeff + (size_t)o * IN * NK;               // [i][k]
        const float* wr = w + (size_t)o * IN;
        float acc = 0.0f;
#pragma unroll
        for (int r = 0; r < IN / 64; ++r) {
            int i = r * 64 + lane;
            acc = fmaf(cf[(size_t)i * NK], wr[i], acc);
        }
#pragma unroll
        for (int off = 32; off >= 1; off >>= 1)
            acc += __shfl_xor(acc, off, 64);
        if (lane == 0) bias[o] = acc;
    }
}

// ---------------------------------------------------------------------------
// Kernel 2: split-K GEMM, explicit LDS double-buffer software pipeline.
//   stage kt+1's global_load_lds issued AFTER the barrier that publishes
//   stage kt -> loads have a full compute phase in flight before the next
//   barrier drains them (vs m97 structure: drain immediately, zero overlap).
// 128x128x32 tile, 256 threads (2x2 waves, 64x64/wave, 4x4 MFMA frags)
// ---------------------------------------------------------------------------
__global__ __launch_bounds__(256, 2) void gemm_splitk(
        const __hip_bfloat16* __restrict__ A,   // [4096][4096]
        const __hip_bfloat16* __restrict__ B,   // [512][4096]
        __hip_bfloat16* __restrict__ P)         // [SPLITK][4096][512] bf16
{
    __shared__ __hip_bfloat16 sA[2 * 128 * 32];   // 16 KB x2
    __shared__ __hip_bfloat16 sB[2 * 128 * 32];

    const int tid = threadIdx.x;
    const int m0 = blockIdx.x * 128;
    const int n0 = blockIdx.y * 128;
    const int z  = blockIdx.z;

    // staging: thread t loads 16B at (row = t/4, col8 = t&3)
    const int lrow = tid >> 2;
    const int lcol = (tid & 3) * 8;
    const __hip_bfloat16* ga = A + (size_t)(m0 + lrow) * KP + z * (KT * 32) + lcol;
    const __hip_bfloat16* gb = B + (size_t)(n0 + lrow) * KP + z * (KT * 32) + lcol;

    // fragment addressing: A[m=lane&15][k=quad*8+j]
    const int lane = tid & 63;
    const int quad = lane >> 4;
    const int l15  = lane & 15;
    const int mw   = (tid >> 6) & 1;
    const int nw   = tid >> 7;
    const int aBase = (mw * 64 + l15) * 32 + quad * 8;
    const int bBase = (nw * 64 + l15) * 32 + quad * 8;

    floatx4 acc[4][4];
#pragma unroll
    for (int i = 0; i < 4; ++i)
#pragma unroll
        for (int j = 0; j < 4; ++j) acc[i][j] = (floatx4)0.0f;

    // prologue: stage 0 into buffer 0
    gload_lds16(ga,                   sA + tid * 8);
    gload_lds16(ga + (size_t)64 * KP, sA + tid * 8 + 2048);
    gload_lds16(gb,                   sB + tid * 8);
    gload_lds16(gb + (size_t)64 * KP, sB + tid * 8 + 2048);
    ga += 32; gb += 32;

    for (int kt = 0; kt < KT; ++kt) {
        __syncthreads();               // publishes buffer kt&1 (drains own vmcnt)
        const int cur = (kt & 1) * 4096;
        if (kt + 1 < KT) {             // wave-uniform
            const int nxt = 4096 - cur;
            gload_lds16(ga,                   sA + nxt + tid * 8);
            gload_lds16(ga + (size_t)64 * KP, sA + nxt + tid * 8 + 2048);
            gload_lds16(gb,                   sB + nxt + tid * 8);
            gload_lds16(gb + (size_t)64 * KP, sB + nxt + tid * 8 + 2048);
            ga += 32; gb += 32;
        }
        short8 af[4], bfr[4];
#pragma unroll
        for (int i = 0; i < 4; ++i)
            af[i] = *(const short8*)(sA + cur + aBase + i * 16 * 32);
#pragma unroll
        for (int j = 0; j < 4; ++j)
            bfr[j] = *(const short8*)(sB + cur + bBase + j * 16 * 32);
#pragma unroll
        for (int i = 0; i < 4; ++i)
#pragma unroll
            for (int j = 0; j < 4; ++j)
                acc[i][j] = __builtin_amdgcn_mfma_f32_16x16x32_bf16(
                                af[i], bfr[j], acc[i][j], 0, 0, 0);
        // no trailing barrier: next iter's barrier protects buffer reuse
    }

    // epilogue: C/D layout col = lane&15, row = quad*4 + reg; bf16 partials
    __hip_bfloat16* Pz = P + (size_t)z * BATCH * OUT;
#pragma unroll
    for (int i = 0; i < 4; ++i) {
        const int r0 = m0 + mw * 64 + i * 16 + quad * 4;
#pragma unroll
        for (int j = 0; j < 4; ++j) {
            const int c = n0 + nw * 64 + j * 16 + l15;
#pragma unroll
            for (int r = 0; r < 4; ++r)
                Pz[(size_t)(r0 + r) * OUT + c] = __float2bfloat16(acc[i][j][r]);
        }
    }
}

// ---------------------------------------------------------------------------
// Kernel 3: out[b,o] = sum_z P[z][b,o] + bias[o]   (8 outputs per thread)
// ---------------------------------------------------------------------------
__global__ __launch_bounds__(256) void reducek(const short* __restrict__ P,
                                               const float* __restrict__ bias,
                                               float* __restrict__ out) {
    const int j = blockIdx.x * 256 + threadIdx.x;   // [0, 2M/8)
    const size_t base = (size_t)j * 8;
    constexpr size_t PLANE = (size_t)BATCH * OUT;   // 2M elements

    float s[8];
    {
        short8 v = *(const short8*)(P + base);
#pragma unroll
        for (int e = 0; e < 8; ++e) s[e] = bf16bits_to_f32(v[e]);
    }
#pragma unroll
    for (int z = 1; z < SPLITK; ++z) {
        short8 v = *(const short8*)(P + z * PLANE + base);
#pragma unroll
        for (int e = 0; e < 8; ++e) s[e] += bf16bits_to_f32(v[e]);
    }
    const int o0 = (int)(base & (OUT - 1));
    const floatx4 b0 = *(const floatx4*)(bias + o0);
    const floatx4 b1 = *(const floatx4*)(bias + o0 + 4);
    floatx4 r0 = {s[0] + b0[0], s[1] + b0[1], s[2] + b0[2], s[3] + b0[3]};
    floatx4 r1 = {s[4] + b1[0], s[5] + b1[1], s[6] + b1[2], s[7] + b1[3]};
    *(floatx4*)(out + base)     = r0;
    *(floatx4*)(out + base + 4) = r1;
}

// ---------------------------------------------------------------------------
extern "C" void kernel_launch(void* const* d_in, const int* in_sizes, int n_in,
                              void* d_out, int out_size, void* d_ws, size_t ws_size,
                              hipStream_t stream) {
    const float* x     = (const float*)d_in[0];   // [4096,512]
    const float* w     = (const float*)d_in[1];   // [512,512]
    const float* coeff = (const float*)d_in[2];   // [512,512,9]
    float* out = (float*)d_out;                   // [4096,512]

    // workspace layout (bytes)
    char* ws = (char*)d_ws;
    __hip_bfloat16* J  = (__hip_bfloat16*)ws;                          // 33,554,432 B
    char* p1c = ws + (size_t)BATCH * KP * 2;
    __hip_bfloat16* Cb = (__hip_bfloat16*)p1c;                         //  4,194,304 B
    char* p2c = p1c + (size_t)OUT * KP * 2;
    __hip_bfloat16* P  = (__hip_bfloat16*)p2c;                         // 16,777,216 B
    float* bias = (float*)(p2c + (size_t)SPLITK * BATCH * OUT * 2);    //      2,048 B

    const int prep_blocks = BATCH * IN / 512 + OUT * IN / 512 + OUT / 4;
    prep<<<prep_blocks, 256, 0, stream>>>(x, w, coeff, J, Cb, bias);
    gemm_splitk<<<dim3(BATCH / 128, OUT / 128, SPLITK), 256, 0, stream>>>(J, Cb, P);
    reducek<<<BATCH * OUT / 8 / 256, 256, 0, stream>>>((const short*)P, bias, out);
}